// Round 8
// baseline (466.954 us; speedup 1.0000x reference)
//
#include <hip/hip_runtime.h>

#define F_IN 128
#define NEG_SLOPE 0.2f
#define SCAN_CHUNK 2048  // 256 threads x 8 elements

typedef __attribute__((ext_vector_type(8))) short bf16x8;
typedef __attribute__((ext_vector_type(4))) float f32x4;

__device__ inline unsigned short f2bf(float f) {  // fp32 -> bf16 RNE
    unsigned int u = __float_as_uint(f);
    unsigned int r = (u + 0x7fffu + ((u >> 16) & 1u)) >> 16;
    return (unsigned short)r;
}
__device__ inline float bf2f(unsigned short h) { return __uint_as_float((unsigned int)h << 16); }
__device__ inline float bflo(unsigned int u) { return __uint_as_float(u << 16); }
__device__ inline float bfhi(unsigned int u) { return __uint_as_float(u & 0xffff0000u); }

// Swizzled ("fragment-order") B index for mfma_f32_16x16x32_bf16 consumption:
// element (n,k) -> ((ct*4+kk)*64 + q*16 + rlo)*8 + j.  A wave's fragment load
// is Bsw[(ct*4+kk)*64 + lane]: lane-contiguous 1 KB, one coalesced transaction.
__device__ inline int bswiz(int n, int k) {
    int ct = n >> 4, rlo = n & 15, kk = k >> 5, q = (k >> 3) & 3, j = k & 7;
    return (((ct * 4 + kk) * 64 + q * 16 + rlo) << 3) + j;
}

// ---------------------------------------------------------------------------
// Prep: zero CSR counters; block 0 computes the 4 projected attention vectors
// v = W@att; blocks 1..96 build swizzled bf16 hi/lo copies of W1/W2.
// ---------------------------------------------------------------------------
__global__ void k_prep(const float* __restrict__ Ws1, const float* __restrict__ Wd1,
                       const float* __restrict__ as1, const float* __restrict__ ad1,
                       const float* __restrict__ Ws2, const float* __restrict__ Wd2,
                       const float* __restrict__ as2, const float* __restrict__ ad2,
                       float* __restrict__ vecs, int* __restrict__ cnt,
                       unsigned short* __restrict__ w1hi, unsigned short* __restrict__ w1lo,
                       unsigned short* __restrict__ w2hi, unsigned short* __restrict__ w2lo,
                       int N) {
    int bid = blockIdx.x, tid = threadIdx.x;
    int i = bid * 256 + tid;
    if (i < N) cnt[i] = 0;
    if (bid == 0 && tid < 128) {
        int f = tid;
        float s1 = 0.f, d1 = 0.f, s2 = 0.f, d2 = 0.f;
        for (int c = 0; c < 128; ++c) {
            s1 += Ws1[f * 128 + c] * as1[c];
            d1 += Wd1[f * 128 + c] * ad1[c];
        }
        for (int c = 0; c < 64; ++c) {
            s2 += Ws2[f * 64 + c] * as2[c];
            d2 += Wd2[f * 64 + c] * ad2[c];
        }
        vecs[f] = s1; vecs[128 + f] = d1; vecs[256 + f] = s2; vecs[384 + f] = d2;
    } else if (bid >= 1 && bid < 65) {          // W1: n<128, k<128
        int idx = (bid - 1) * 256 + tid;        // < 16384
        int n = idx >> 7, k = idx & 127;
        float w = Ws1[k * 128 + n];
        unsigned short h = f2bf(w);
        int si = bswiz(n, k);
        w1hi[si] = h;
        w1lo[si] = f2bf(w - bf2f(h));
    } else if (bid >= 65 && bid < 97) {         // W2: n<64, k<128
        int idx = (bid - 65) * 256 + tid;       // < 8192
        int n = idx >> 7, k = idx & 127;
        float w = Ws2[k * 64 + n];
        unsigned short h = f2bf(w);
        int si = bswiz(n, k);
        w2hi[si] = h;
        w2lo[si] = f2bf(w - bf2f(h));
    }
}

// ---------------------------------------------------------------------------
// CSR build: hist (pure count, no rank) -> fused scan -> cursor place.
// ---------------------------------------------------------------------------
__global__ void k_hist(const int* __restrict__ dsts, int* __restrict__ cnt, int E) {
    int e0 = (blockIdx.x * 256 + threadIdx.x) * 4;
    if (e0 + 4 <= E) {
        int4 d4 = *(const int4*)(dsts + e0);
        atomicAdd(&cnt[d4.x], 1);
        atomicAdd(&cnt[d4.y], 1);
        atomicAdd(&cnt[d4.z], 1);
        atomicAdd(&cnt[d4.w], 1);
    } else {
        for (int e = e0; e < E; ++e) atomicAdd(&cnt[dsts[e]], 1);
    }
}

__global__ void k_blocksum(const int* __restrict__ cnt, int* __restrict__ bsum, int N) {
    __shared__ int sh[256];
    int t = threadIdx.x;
    long long base = (long long)blockIdx.x * SCAN_CHUNK + (long long)t * 8;
    int s = 0;
    #pragma unroll
    for (int k = 0; k < 8; ++k) {
        long long i = base + k;
        if (i < N) s += cnt[i];
    }
    sh[t] = s;
    __syncthreads();
    for (int off = 128; off; off >>= 1) {
        if (t < off) sh[t] += sh[t + off];
        __syncthreads();
    }
    if (t == 0) bsum[blockIdx.x] = sh[0];
}

// Fused: per-block bsum prefix (uniform scalar loop over <=49 entries) +
// chunk-local scan; writes rowptr AND cursor copy; last block writes rowptr[N].
__global__ void k_scan_chunks(const int* __restrict__ cnt, const int* __restrict__ bsum,
                              int* __restrict__ rowptr, int* __restrict__ cursor,
                              int nb, int N) {
    __shared__ int sh[256];
    int t = threadIdx.x;
    int bid = blockIdx.x;
    int pre = 0;
    for (int b = 0; b < bid; ++b) pre += bsum[b];   // uniform -> s_loads
    long long base = (long long)bid * SCAN_CHUNK + (long long)t * 8;
    int loc[8];
    int s = 0;
    #pragma unroll
    for (int k = 0; k < 8; ++k) {
        long long i = base + k;
        int v = (i < N) ? cnt[i] : 0;
        loc[k] = s;
        s += v;
    }
    sh[t] = s;
    __syncthreads();
    for (int off = 1; off < 256; off <<= 1) {
        int tmp = (t >= off) ? sh[t - off] : 0;
        __syncthreads();
        sh[t] += tmp;
        __syncthreads();
    }
    int toff = pre + sh[t] - s;
    #pragma unroll
    for (int k = 0; k < 8; ++k) {
        long long i = base + k;
        if (i < N) {
            int val = toff + loc[k];
            rowptr[i] = val;
            cursor[i] = val;
        }
    }
    if (bid == nb - 1 && t == 255) rowptr[N] = pre + sh[255];
}

__global__ void k_place(const int* __restrict__ srcs, const int* __restrict__ dsts,
                        int* __restrict__ cursor, int* __restrict__ perm_src, int E) {
    int e = blockIdx.x * 256 + threadIdx.x;
    if (e >= E) return;
    int pos = atomicAdd(&cursor[dsts[e]], 1);
    perm_src[pos] = srcs[e];
}

// ---------------------------------------------------------------------------
// MFMA GEMM: H(bf16)[N][COLS] = X[N][128] @ W[128][COLS], fused rowdots.
// Swizzled B (coalesced 1 KB fragment loads) + 2 row-tiles per wave.
// Layer1 (!ABF16): fp32 X split bf16 hi/lo, 3 MFMAs/frag; Layer2: 2 MFMAs.
// ---------------------------------------------------------------------------
template <int COLS, bool ABF16>
__launch_bounds__(256)
__global__ void k_gemm_mfma(const void* __restrict__ Xv,
                            const unsigned short* __restrict__ Bh,
                            const unsigned short* __restrict__ Bl,
                            const float* __restrict__ vecs_s,
                            const float* __restrict__ vecs_d,
                            unsigned short* __restrict__ H,
                            float* __restrict__ a_s, float* __restrict__ a_d, int N) {
    int tid = threadIdx.x;
    int wave = tid >> 6, lane = tid & 63;
    int q = lane >> 4, rlo = lane & 15;
    long long wrow0 = (long long)blockIdx.x * 128 + wave * 32;

    bf16x8 Ahi[2][4], Alo[2][4];
    #pragma unroll
    for (int rt = 0; rt < 2; ++rt) {
        long long r = wrow0 + rt * 16 + rlo;
        long long rr = (r < N) ? r : (long long)(N - 1);  // clamp loads
        float ps = 0.f, pd = 0.f;
        #pragma unroll
        for (int kk = 0; kk < 4; ++kk) {
            int k0 = kk * 32 + q * 8;
            float xv[8];
            if constexpr (ABF16) {
                const unsigned short* Xu = (const unsigned short*)Xv;
                bf16x8 av = *(const bf16x8*)(Xu + rr * 128 + k0);
                Ahi[rt][kk] = av;
                #pragma unroll
                for (int j = 0; j < 8; ++j) xv[j] = bf2f((unsigned short)av[j]);
            } else {
                const float* Xf = (const float*)Xv;
                float4 x0 = *(const float4*)(Xf + rr * 128 + k0);
                float4 x1 = *(const float4*)(Xf + rr * 128 + k0 + 4);
                xv[0] = x0.x; xv[1] = x0.y; xv[2] = x0.z; xv[3] = x0.w;
                xv[4] = x1.x; xv[5] = x1.y; xv[6] = x1.z; xv[7] = x1.w;
                bf16x8 ah, al;
                #pragma unroll
                for (int j = 0; j < 8; ++j) {
                    unsigned short h = f2bf(xv[j]);
                    ah[j] = (short)h;
                    al[j] = (short)f2bf(xv[j] - bf2f(h));
                }
                Ahi[rt][kk] = ah; Alo[rt][kk] = al;
            }
            float4 vs0 = *(const float4*)(vecs_s + k0);
            float4 vs1 = *(const float4*)(vecs_s + k0 + 4);
            float4 vd0 = *(const float4*)(vecs_d + k0);
            float4 vd1 = *(const float4*)(vecs_d + k0 + 4);
            ps += xv[0] * vs0.x + xv[1] * vs0.y + xv[2] * vs0.z + xv[3] * vs0.w
                + xv[4] * vs1.x + xv[5] * vs1.y + xv[6] * vs1.z + xv[7] * vs1.w;
            pd += xv[0] * vd0.x + xv[1] * vd0.y + xv[2] * vd0.z + xv[3] * vd0.w
                + xv[4] * vd1.x + xv[5] * vd1.y + xv[6] * vd1.z + xv[7] * vd1.w;
        }
        ps += __shfl_xor(ps, 16); ps += __shfl_xor(ps, 32);
        pd += __shfl_xor(pd, 16); pd += __shfl_xor(pd, 32);
        if (q == 0 && r < N) { a_s[r] = ps; a_d[r] = pd; }
    }

    const bf16x8* Bh8 = (const bf16x8*)Bh;
    const bf16x8* Bl8 = (const bf16x8*)Bl;
    #pragma unroll 1   // keep rolled: bounds VGPRs; 8 loads in flight per iter
    for (int ct = 0; ct < COLS / 16; ++ct) {
        bf16x8 bh[4], bl[4];
        #pragma unroll
        for (int kk = 0; kk < 4; ++kk) {
            bh[kk] = Bh8[(ct * 4 + kk) * 64 + lane];
            bl[kk] = Bl8[(ct * 4 + kk) * 64 + lane];
        }
        f32x4 acc0 = {0.f, 0.f, 0.f, 0.f};
        f32x4 acc1 = {0.f, 0.f, 0.f, 0.f};
        #pragma unroll
        for (int kk = 0; kk < 4; ++kk) {
            acc0 = __builtin_amdgcn_mfma_f32_16x16x32_bf16(Ahi[0][kk], bh[kk], acc0, 0, 0, 0);
            acc1 = __builtin_amdgcn_mfma_f32_16x16x32_bf16(Ahi[1][kk], bh[kk], acc1, 0, 0, 0);
            if constexpr (!ABF16) {
                acc0 = __builtin_amdgcn_mfma_f32_16x16x32_bf16(Alo[0][kk], bh[kk], acc0, 0, 0, 0);
                acc1 = __builtin_amdgcn_mfma_f32_16x16x32_bf16(Alo[1][kk], bh[kk], acc1, 0, 0, 0);
            }
            acc0 = __builtin_amdgcn_mfma_f32_16x16x32_bf16(Ahi[0][kk], bl[kk], acc0, 0, 0, 0);
            acc1 = __builtin_amdgcn_mfma_f32_16x16x32_bf16(Ahi[1][kk], bl[kk], acc1, 0, 0, 0);
        }
        #pragma unroll
        for (int i2 = 0; i2 < 4; ++i2) {
            long long o0 = wrow0 + q * 4 + i2;
            long long o1 = wrow0 + 16 + q * 4 + i2;
            if (o0 < N) H[o0 * COLS + ct * 16 + rlo] = f2bf(acc0[i2]);
            if (o1 < N) H[o1 * COLS + ct * 16 + rlo] = f2bf(acc1[i2]);
        }
    }
}

// ---------------------------------------------------------------------------
// Layer-1 aggregate (C=128): one wave per dst row; 8-deep unroll; scalar-path
// broadcasts (readfirstlane).  Writes relu(agg + b1) as packed bf16.
// At the random-256B L3 fetch ceiling (~3.1 TB/s) — do not touch.
// ---------------------------------------------------------------------------
__launch_bounds__(256)
__global__ void k_agg128(const int* __restrict__ rowptr, const int* __restrict__ perm,
                         const float* __restrict__ a_s, const float* __restrict__ a_d,
                         const unsigned short* __restrict__ H, const float* __restrict__ bias,
                         unsigned short* __restrict__ out_bf, int N) {
    int wave = (int)(((long long)blockIdx.x * 256 + threadIdx.x) >> 6);
    int lane = threadIdx.x & 63;
    if (wave >= N) return;
    int beg = __builtin_amdgcn_readfirstlane(rowptr[wave]);
    int end = __builtin_amdgcn_readfirstlane(rowptr[wave + 1]);
    float ad = __uint_as_float(__builtin_amdgcn_readfirstlane(__float_as_uint(a_d[wave])));

    const unsigned int* H32 = (const unsigned int*)H;  // 64 uints/row
    float acc0 = 0.f, acc1 = 0.f, wsum = 0.f;
    int i = beg;
    for (; i + 8 <= end; i += 8) {
        int s[8];
        unsigned int v[8];
        #pragma unroll
        for (int j = 0; j < 8; ++j)
            s[j] = __builtin_amdgcn_readfirstlane(perm[i + j]);
        #pragma unroll
        for (int j = 0; j < 8; ++j)
            v[j] = H32[(long long)s[j] * 64 + lane];
        #pragma unroll
        for (int j = 0; j < 8; ++j) {
            float t = a_s[s[j]] + ad;
            t = t > 0.f ? t : NEG_SLOPE * t;
            float w = __expf(t);
            acc0 += w * bflo(v[j]);
            acc1 += w * bfhi(v[j]);
            wsum += w;
        }
    }
    for (; i < end; ++i) {
        int s = __builtin_amdgcn_readfirstlane(perm[i]);
        unsigned int v = H32[(long long)s * 64 + lane];
        float t = a_s[s] + ad;
        t = t > 0.f ? t : NEG_SLOPE * t;
        float w = __expf(t);
        acc0 += w * bflo(v); acc1 += w * bfhi(v);
        wsum += w;
    }
    float inv = (wsum > 0.f) ? __fdividef(1.f, wsum) : 0.f;  // deg-0 -> bias only
    float o0 = fmaxf(acc0 * inv + bias[2 * lane], 0.f);      // + b1, relu
    float o1 = fmaxf(acc1 * inv + bias[2 * lane + 1], 0.f);
    unsigned int pk = (unsigned int)f2bf(o0) | ((unsigned int)f2bf(o1) << 16);
    ((unsigned int*)out_bf)[(long long)wave * 64 + lane] = pk;
}

// ---------------------------------------------------------------------------
// Layer-2 aggregate (C=64): half-wave per edge, 8-deep unroll (16 rows in
// flight), cross-half shfl merge.
// ---------------------------------------------------------------------------
__launch_bounds__(256)
__global__ void k_agg64(const int* __restrict__ rowptr, const int* __restrict__ perm,
                        const float* __restrict__ a_s, const float* __restrict__ a_d,
                        const unsigned short* __restrict__ H, const float* __restrict__ bias,
                        float* __restrict__ out, int N) {
    int wave = (int)(((long long)blockIdx.x * 256 + threadIdx.x) >> 6);
    int lane = threadIdx.x & 63;
    if (wave >= N) return;
    int c = lane & 31, h = lane >> 5;  // half-wave id
    int beg = __builtin_amdgcn_readfirstlane(rowptr[wave]);
    int end = __builtin_amdgcn_readfirstlane(rowptr[wave + 1]);
    float ad = __uint_as_float(__builtin_amdgcn_readfirstlane(__float_as_uint(a_d[wave])));

    const unsigned int* H32 = (const unsigned int*)H;  // 32 uints/row
    float acc0 = 0.f, acc1 = 0.f, wsum = 0.f;
    int base = beg;
    for (; base + 16 <= end; base += 16) {
        int s[8];
        unsigned int v[8];
        #pragma unroll
        for (int j = 0; j < 8; ++j)
            s[j] = perm[base + h + 2 * j];
        #pragma unroll
        for (int j = 0; j < 8; ++j)
            v[j] = H32[(long long)s[j] * 32 + c];
        #pragma unroll
        for (int j = 0; j < 8; ++j) {
            float t = a_s[s[j]] + ad;
            t = t > 0.f ? t : NEG_SLOPE * t;
            float w = __expf(t);
            acc0 += w * bflo(v[j]);
            acc1 += w * bfhi(v[j]);
            wsum += w;
        }
    }
    for (; base + 8 <= end; base += 8) {
        int s[4];
        unsigned int v[4];
        #pragma unroll
        for (int j = 0; j < 4; ++j)
            s[j] = perm[base + h + 2 * j];
        #pragma unroll
        for (int j = 0; j < 4; ++j)
            v[j] = H32[(long long)s[j] * 32 + c];
        #pragma unroll
        for (int j = 0; j < 4; ++j) {
            float t = a_s[s[j]] + ad;
            t = t > 0.f ? t : NEG_SLOPE * t;
            float w = __expf(t);
            acc0 += w * bflo(v[j]);
            acc1 += w * bfhi(v[j]);
            wsum += w;
        }
    }
    for (int i = base + h; i < end; i += 2) {
        int s = perm[i];
        unsigned int v = H32[(long long)s * 32 + c];
        float t = a_s[s] + ad;
        t = t > 0.f ? t : NEG_SLOPE * t;
        float w = __expf(t);
        acc0 += w * bflo(v); acc1 += w * bfhi(v);
        wsum += w;
    }
    acc0 += __shfl_xor(acc0, 32);
    acc1 += __shfl_xor(acc1, 32);
    wsum += __shfl_xor(wsum, 32);
    if (h == 0) {
        float inv = (wsum > 0.f) ? __fdividef(1.f, wsum) : 0.f;
        float2 o;
        o.x = acc0 * inv + bias[2 * c];
        o.y = acc1 * inv + bias[2 * c + 1];
        *(float2*)(out + (long long)wave * 64 + 2 * c) = o;
    }
}

extern "C" void kernel_launch(void* const* d_in, const int* in_sizes, int n_in,
                              void* d_out, int out_size, void* d_ws, size_t ws_size,
                              hipStream_t stream) {
    const float* x   = (const float*)d_in[0];
    const int*   ei  = (const int*)d_in[1];
    const float* Ws1 = (const float*)d_in[2];
    const float* Wd1 = (const float*)d_in[3];
    const float* as1 = (const float*)d_in[4];
    const float* ad1 = (const float*)d_in[5];
    const float* b1  = (const float*)d_in[6];
    const float* Ws2 = (const float*)d_in[7];
    const float* Wd2 = (const float*)d_in[8];
    const float* as2 = (const float*)d_in[9];
    const float* ad2 = (const float*)d_in[10];
    const float* b2  = (const float*)d_in[11];
    float* out = (float*)d_out;

    const int N = in_sizes[0] / F_IN;   // 100000
    const int E = in_sizes[1] / 2;      // 1600000
    const int* srcs = ei;
    const int* dsts = ei + E;

    // Workspace (~60 MB).
    unsigned short* hbuf = (unsigned short*)d_ws;              // N*128 bf16
    unsigned short* x2bf = hbuf + (size_t)N * 128;             // N*128 bf16
    int*   perm   = (int*)(x2bf + (size_t)N * 128);            // E (src only)
    float* a_s1   = (float*)(perm + E);
    float* a_d1   = a_s1 + N;
    float* a_s2   = a_d1 + N;
    float* a_d2   = a_s2 + N;
    int*   cnt    = (int*)(a_d2 + N);                          // N
    int*   rowptr = cnt + N;                                   // N+1 (pad to +4)
    int*   cursor = rowptr + N + 4;                            // N
    int*   bsum   = cursor + N;                                // 64
    unsigned short* w1hi = (unsigned short*)(bsum + 64);       // 16384 (swizzled)
    unsigned short* w1lo = w1hi + 16384;
    unsigned short* w2hi = w1lo + 16384;                       // 8192 (swizzled)
    unsigned short* w2lo = w2hi + 8192;
    float* vecs   = (float*)(w2lo + 8192);                     // 512

    const int nb = (N + SCAN_CHUNK - 1) / SCAN_CHUNK;

    // ---- prep (cnt zero + attention vecs + swizzled W hi/lo) ----
    k_prep<<<(N + 255) / 256, 256, 0, stream>>>(Ws1, Wd1, as1, ad1, Ws2, Wd2,
                                                as2, ad2, vecs, cnt,
                                                w1hi, w1lo, w2hi, w2lo, N);
    // ---- CSR build (once, reused by both layers) ----
    k_hist<<<(E / 4 + 255) / 256, 256, 0, stream>>>(dsts, cnt, E);
    k_blocksum<<<nb, 256, 0, stream>>>(cnt, bsum, N);
    k_scan_chunks<<<nb, 256, 0, stream>>>(cnt, bsum, rowptr, cursor, nb, N);
    k_place<<<(E + 255) / 256, 256, 0, stream>>>(srcs, dsts, cursor, perm, E);

    // ---- Layer 1: fp32 X, split-bf16 MFMA ----
    k_gemm_mfma<128, false><<<(N + 127) / 128, 256, 0, stream>>>(
        x, w1hi, w1lo, vecs, vecs + 128, hbuf, a_s1, a_d1, N);
    k_agg128<<<(N + 3) / 4, 256, 0, stream>>>(
        rowptr, perm, a_s1, a_d1, hbuf, b1, x2bf, N);

    // ---- Layer 2: bf16 X (relu'd, b1 folded in by agg) ----
    k_gemm_mfma<64, true><<<(N + 127) / 128, 256, 0, stream>>>(
        x2bf, w2hi, w2lo, vecs + 256, vecs + 384, hbuf, a_s2, a_d2, N);
    k_agg64<<<(N + 3) / 4, 256, 0, stream>>>(
        rowptr, perm, a_s2, a_d2, hbuf, b2, out, N);
}

// Round 9
// 379.591 us; speedup vs baseline: 1.2302x; 1.2302x over previous
//
#include <hip/hip_runtime.h>

#define F_IN 128
#define NEG_SLOPE 0.2f
#define SCAN_CHUNK 2048  // 256 threads x 8 elements

typedef __attribute__((ext_vector_type(8))) short bf16x8;
typedef __attribute__((ext_vector_type(4))) float f32x4;

__device__ inline unsigned short f2bf(float f) {  // fp32 -> bf16 RNE
    unsigned int u = __float_as_uint(f);
    unsigned int r = (u + 0x7fffu + ((u >> 16) & 1u)) >> 16;
    return (unsigned short)r;
}
__device__ inline float bf2f(unsigned short h) { return __uint_as_float((unsigned int)h << 16); }
__device__ inline float bflo(unsigned int u) { return __uint_as_float(u << 16); }
__device__ inline float bfhi(unsigned int u) { return __uint_as_float(u & 0xffff0000u); }

// Swizzled ("fragment-order") B index for mfma_f32_16x16x32_bf16 consumption:
// element (n,k) -> ((ct*4+kk)*64 + q*16 + rlo)*8 + j.  A wave's fragment load
// is Bsw[(ct*4+kk)*64 + lane]: lane-contiguous 1 KB, one coalesced transaction.
__device__ inline int bswiz(int n, int k) {
    int ct = n >> 4, rlo = n & 15, kk = k >> 5, q = (k >> 3) & 3, j = k & 7;
    return (((ct * 4 + kk) * 64 + q * 16 + rlo) << 3) + j;
}

// ---------------------------------------------------------------------------
// Prep: zero CSR counters; block 0 computes the 4 projected attention vectors
// v = W@att; blocks 1..96 build swizzled bf16 hi/lo copies of W1/W2.
// ---------------------------------------------------------------------------
__global__ void k_prep(const float* __restrict__ Ws1, const float* __restrict__ Wd1,
                       const float* __restrict__ as1, const float* __restrict__ ad1,
                       const float* __restrict__ Ws2, const float* __restrict__ Wd2,
                       const float* __restrict__ as2, const float* __restrict__ ad2,
                       float* __restrict__ vecs, int* __restrict__ cnt,
                       unsigned short* __restrict__ w1hi, unsigned short* __restrict__ w1lo,
                       unsigned short* __restrict__ w2hi, unsigned short* __restrict__ w2lo,
                       int N) {
    int bid = blockIdx.x, tid = threadIdx.x;
    int i = bid * 256 + tid;
    if (i < N) cnt[i] = 0;
    if (bid == 0 && tid < 128) {
        int f = tid;
        float s1 = 0.f, d1 = 0.f, s2 = 0.f, d2 = 0.f;
        for (int c = 0; c < 128; ++c) {
            s1 += Ws1[f * 128 + c] * as1[c];
            d1 += Wd1[f * 128 + c] * ad1[c];
        }
        for (int c = 0; c < 64; ++c) {
            s2 += Ws2[f * 64 + c] * as2[c];
            d2 += Wd2[f * 64 + c] * ad2[c];
        }
        vecs[f] = s1; vecs[128 + f] = d1; vecs[256 + f] = s2; vecs[384 + f] = d2;
    } else if (bid >= 1 && bid < 65) {          // W1: n<128, k<128
        int idx = (bid - 1) * 256 + tid;        // < 16384
        int n = idx >> 7, k = idx & 127;
        float w = Ws1[k * 128 + n];
        unsigned short h = f2bf(w);
        int si = bswiz(n, k);
        w1hi[si] = h;
        w1lo[si] = f2bf(w - bf2f(h));
    } else if (bid >= 65 && bid < 97) {         // W2: n<64, k<128
        int idx = (bid - 65) * 256 + tid;       // < 8192
        int n = idx >> 7, k = idx & 127;
        float w = Ws2[k * 64 + n];
        unsigned short h = f2bf(w);
        int si = bswiz(n, k);
        w2hi[si] = h;
        w2lo[si] = f2bf(w - bf2f(h));
    }
}

// ---------------------------------------------------------------------------
// CSR build, round-7 split restored (returning-atomic place regressed 2.4x):
// hist returns rank (latency overlapped kernel-wide, nothing depends on it
// in-kernel) -> fused scan -> place = pure loads + independent scatters.
// Both hist and place do 4 edges/thread (int4) for deeper MLP.
// ---------------------------------------------------------------------------
__global__ void k_hist(const int* __restrict__ dsts, int* __restrict__ cnt,
                       int* __restrict__ rank, int E) {
    int e0 = (blockIdx.x * 256 + threadIdx.x) * 4;
    if (e0 + 4 <= E) {
        int4 d4 = *(const int4*)(dsts + e0);
        int4 r4;
        r4.x = atomicAdd(&cnt[d4.x], 1);
        r4.y = atomicAdd(&cnt[d4.y], 1);
        r4.z = atomicAdd(&cnt[d4.z], 1);
        r4.w = atomicAdd(&cnt[d4.w], 1);
        *(int4*)(rank + e0) = r4;
    } else {
        for (int e = e0; e < E; ++e) rank[e] = atomicAdd(&cnt[dsts[e]], 1);
    }
}

__global__ void k_blocksum(const int* __restrict__ cnt, int* __restrict__ bsum, int N) {
    __shared__ int sh[256];
    int t = threadIdx.x;
    long long base = (long long)blockIdx.x * SCAN_CHUNK + (long long)t * 8;
    int s = 0;
    #pragma unroll
    for (int k = 0; k < 8; ++k) {
        long long i = base + k;
        if (i < N) s += cnt[i];
    }
    sh[t] = s;
    __syncthreads();
    for (int off = 128; off; off >>= 1) {
        if (t < off) sh[t] += sh[t + off];
        __syncthreads();
    }
    if (t == 0) bsum[blockIdx.x] = sh[0];
}

// Fused: per-block bsum prefix (uniform scalar loop over <=49 entries) +
// chunk-local scan; last block writes rowptr[N].
__global__ void k_scan_chunks(const int* __restrict__ cnt, const int* __restrict__ bsum,
                              int* __restrict__ rowptr, int nb, int N) {
    __shared__ int sh[256];
    int t = threadIdx.x;
    int bid = blockIdx.x;
    int pre = 0;
    for (int b = 0; b < bid; ++b) pre += bsum[b];   // uniform -> s_loads
    long long base = (long long)bid * SCAN_CHUNK + (long long)t * 8;
    int loc[8];
    int s = 0;
    #pragma unroll
    for (int k = 0; k < 8; ++k) {
        long long i = base + k;
        int v = (i < N) ? cnt[i] : 0;
        loc[k] = s;
        s += v;
    }
    sh[t] = s;
    __syncthreads();
    for (int off = 1; off < 256; off <<= 1) {
        int tmp = (t >= off) ? sh[t - off] : 0;
        __syncthreads();
        sh[t] += tmp;
        __syncthreads();
    }
    int toff = pre + sh[t] - s;
    #pragma unroll
    for (int k = 0; k < 8; ++k) {
        long long i = base + k;
        if (i < N) rowptr[i] = toff + loc[k];
    }
    if (bid == nb - 1 && t == 255) rowptr[N] = pre + sh[255];
}

__global__ void k_place(const int* __restrict__ srcs, const int* __restrict__ dsts,
                        const int* __restrict__ rowptr, const int* __restrict__ rank,
                        int* __restrict__ perm_src, int E) {
    int e0 = (blockIdx.x * 256 + threadIdx.x) * 4;
    if (e0 + 4 <= E) {
        int4 s4 = *(const int4*)(srcs + e0);
        int4 d4 = *(const int4*)(dsts + e0);
        int4 r4 = *(const int4*)(rank + e0);
        int p0 = rowptr[d4.x], p1 = rowptr[d4.y];
        int p2 = rowptr[d4.z], p3 = rowptr[d4.w];
        perm_src[p0 + r4.x] = s4.x;
        perm_src[p1 + r4.y] = s4.y;
        perm_src[p2 + r4.z] = s4.z;
        perm_src[p3 + r4.w] = s4.w;
    } else {
        for (int e = e0; e < E; ++e)
            perm_src[rowptr[dsts[e]] + rank[e]] = srcs[e];
    }
}

// ---------------------------------------------------------------------------
// MFMA GEMM: H(bf16)[N][COLS] = X[N][128] @ W[128][COLS], fused rowdots.
// Swizzled B (coalesced 1 KB fragment loads) + 2 row-tiles per wave.
// Layer1 (!ABF16): fp32 X split bf16 hi/lo, 3 MFMAs/frag; Layer2: 2 MFMAs.
// ---------------------------------------------------------------------------
template <int COLS, bool ABF16>
__launch_bounds__(256)
__global__ void k_gemm_mfma(const void* __restrict__ Xv,
                            const unsigned short* __restrict__ Bh,
                            const unsigned short* __restrict__ Bl,
                            const float* __restrict__ vecs_s,
                            const float* __restrict__ vecs_d,
                            unsigned short* __restrict__ H,
                            float* __restrict__ a_s, float* __restrict__ a_d, int N) {
    int tid = threadIdx.x;
    int wave = tid >> 6, lane = tid & 63;
    int q = lane >> 4, rlo = lane & 15;
    long long wrow0 = (long long)blockIdx.x * 128 + wave * 32;

    bf16x8 Ahi[2][4], Alo[2][4];
    #pragma unroll
    for (int rt = 0; rt < 2; ++rt) {
        long long r = wrow0 + rt * 16 + rlo;
        long long rr = (r < N) ? r : (long long)(N - 1);  // clamp loads
        float ps = 0.f, pd = 0.f;
        #pragma unroll
        for (int kk = 0; kk < 4; ++kk) {
            int k0 = kk * 32 + q * 8;
            float xv[8];
            if constexpr (ABF16) {
                const unsigned short* Xu = (const unsigned short*)Xv;
                bf16x8 av = *(const bf16x8*)(Xu + rr * 128 + k0);
                Ahi[rt][kk] = av;
                #pragma unroll
                for (int j = 0; j < 8; ++j) xv[j] = bf2f((unsigned short)av[j]);
            } else {
                const float* Xf = (const float*)Xv;
                float4 x0 = *(const float4*)(Xf + rr * 128 + k0);
                float4 x1 = *(const float4*)(Xf + rr * 128 + k0 + 4);
                xv[0] = x0.x; xv[1] = x0.y; xv[2] = x0.z; xv[3] = x0.w;
                xv[4] = x1.x; xv[5] = x1.y; xv[6] = x1.z; xv[7] = x1.w;
                bf16x8 ah, al;
                #pragma unroll
                for (int j = 0; j < 8; ++j) {
                    unsigned short h = f2bf(xv[j]);
                    ah[j] = (short)h;
                    al[j] = (short)f2bf(xv[j] - bf2f(h));
                }
                Ahi[rt][kk] = ah; Alo[rt][kk] = al;
            }
            float4 vs0 = *(const float4*)(vecs_s + k0);
            float4 vs1 = *(const float4*)(vecs_s + k0 + 4);
            float4 vd0 = *(const float4*)(vecs_d + k0);
            float4 vd1 = *(const float4*)(vecs_d + k0 + 4);
            ps += xv[0] * vs0.x + xv[1] * vs0.y + xv[2] * vs0.z + xv[3] * vs0.w
                + xv[4] * vs1.x + xv[5] * vs1.y + xv[6] * vs1.z + xv[7] * vs1.w;
            pd += xv[0] * vd0.x + xv[1] * vd0.y + xv[2] * vd0.z + xv[3] * vd0.w
                + xv[4] * vd1.x + xv[5] * vd1.y + xv[6] * vd1.z + xv[7] * vd1.w;
        }
        ps += __shfl_xor(ps, 16); ps += __shfl_xor(ps, 32);
        pd += __shfl_xor(pd, 16); pd += __shfl_xor(pd, 32);
        if (q == 0 && r < N) { a_s[r] = ps; a_d[r] = pd; }
    }

    const bf16x8* Bh8 = (const bf16x8*)Bh;
    const bf16x8* Bl8 = (const bf16x8*)Bl;
    #pragma unroll 1   // keep rolled: bounds VGPRs; 8 loads in flight per iter
    for (int ct = 0; ct < COLS / 16; ++ct) {
        bf16x8 bh[4], bl[4];
        #pragma unroll
        for (int kk = 0; kk < 4; ++kk) {
            bh[kk] = Bh8[(ct * 4 + kk) * 64 + lane];
            bl[kk] = Bl8[(ct * 4 + kk) * 64 + lane];
        }
        f32x4 acc0 = {0.f, 0.f, 0.f, 0.f};
        f32x4 acc1 = {0.f, 0.f, 0.f, 0.f};
        #pragma unroll
        for (int kk = 0; kk < 4; ++kk) {
            acc0 = __builtin_amdgcn_mfma_f32_16x16x32_bf16(Ahi[0][kk], bh[kk], acc0, 0, 0, 0);
            acc1 = __builtin_amdgcn_mfma_f32_16x16x32_bf16(Ahi[1][kk], bh[kk], acc1, 0, 0, 0);
            if constexpr (!ABF16) {
                acc0 = __builtin_amdgcn_mfma_f32_16x16x32_bf16(Alo[0][kk], bh[kk], acc0, 0, 0, 0);
                acc1 = __builtin_amdgcn_mfma_f32_16x16x32_bf16(Alo[1][kk], bh[kk], acc1, 0, 0, 0);
            }
            acc0 = __builtin_amdgcn_mfma_f32_16x16x32_bf16(Ahi[0][kk], bl[kk], acc0, 0, 0, 0);
            acc1 = __builtin_amdgcn_mfma_f32_16x16x32_bf16(Ahi[1][kk], bl[kk], acc1, 0, 0, 0);
        }
        #pragma unroll
        for (int i2 = 0; i2 < 4; ++i2) {
            long long o0 = wrow0 + q * 4 + i2;
            long long o1 = wrow0 + 16 + q * 4 + i2;
            if (o0 < N) H[o0 * COLS + ct * 16 + rlo] = f2bf(acc0[i2]);
            if (o1 < N) H[o1 * COLS + ct * 16 + rlo] = f2bf(acc1[i2]);
        }
    }
}

// ---------------------------------------------------------------------------
// Layer-1 aggregate (C=128): one wave per dst row; 8-deep unroll; scalar-path
// broadcasts (readfirstlane).  Writes relu(agg + b1) as packed bf16.
// At the random-row fetch ceiling (~3.1 TB/s, FETCH ~191 MB) — structural.
// ---------------------------------------------------------------------------
__launch_bounds__(256)
__global__ void k_agg128(const int* __restrict__ rowptr, const int* __restrict__ perm,
                         const float* __restrict__ a_s, const float* __restrict__ a_d,
                         const unsigned short* __restrict__ H, const float* __restrict__ bias,
                         unsigned short* __restrict__ out_bf, int N) {
    int wave = (int)(((long long)blockIdx.x * 256 + threadIdx.x) >> 6);
    int lane = threadIdx.x & 63;
    if (wave >= N) return;
    int beg = __builtin_amdgcn_readfirstlane(rowptr[wave]);
    int end = __builtin_amdgcn_readfirstlane(rowptr[wave + 1]);
    float ad = __uint_as_float(__builtin_amdgcn_readfirstlane(__float_as_uint(a_d[wave])));

    const unsigned int* H32 = (const unsigned int*)H;  // 64 uints/row
    float acc0 = 0.f, acc1 = 0.f, wsum = 0.f;
    int i = beg;
    for (; i + 8 <= end; i += 8) {
        int s[8];
        unsigned int v[8];
        #pragma unroll
        for (int j = 0; j < 8; ++j)
            s[j] = __builtin_amdgcn_readfirstlane(perm[i + j]);
        #pragma unroll
        for (int j = 0; j < 8; ++j)
            v[j] = H32[(long long)s[j] * 64 + lane];
        #pragma unroll
        for (int j = 0; j < 8; ++j) {
            float t = a_s[s[j]] + ad;
            t = t > 0.f ? t : NEG_SLOPE * t;
            float w = __expf(t);
            acc0 += w * bflo(v[j]);
            acc1 += w * bfhi(v[j]);
            wsum += w;
        }
    }
    for (; i < end; ++i) {
        int s = __builtin_amdgcn_readfirstlane(perm[i]);
        unsigned int v = H32[(long long)s * 64 + lane];
        float t = a_s[s] + ad;
        t = t > 0.f ? t : NEG_SLOPE * t;
        float w = __expf(t);
        acc0 += w * bflo(v); acc1 += w * bfhi(v);
        wsum += w;
    }
    float inv = (wsum > 0.f) ? __fdividef(1.f, wsum) : 0.f;  // deg-0 -> bias only
    float o0 = fmaxf(acc0 * inv + bias[2 * lane], 0.f);      // + b1, relu
    float o1 = fmaxf(acc1 * inv + bias[2 * lane + 1], 0.f);
    unsigned int pk = (unsigned int)f2bf(o0) | ((unsigned int)f2bf(o1) << 16);
    ((unsigned int*)out_bf)[(long long)wave * 64 + lane] = pk;
}

// ---------------------------------------------------------------------------
// Layer-2 aggregate (C=64): half-wave per edge, 8-deep unroll (16 rows in
// flight), cross-half shfl merge.
// ---------------------------------------------------------------------------
__launch_bounds__(256)
__global__ void k_agg64(const int* __restrict__ rowptr, const int* __restrict__ perm,
                        const float* __restrict__ a_s, const float* __restrict__ a_d,
                        const unsigned short* __restrict__ H, const float* __restrict__ bias,
                        float* __restrict__ out, int N) {
    int wave = (int)(((long long)blockIdx.x * 256 + threadIdx.x) >> 6);
    int lane = threadIdx.x & 63;
    if (wave >= N) return;
    int c = lane & 31, h = lane >> 5;  // half-wave id
    int beg = __builtin_amdgcn_readfirstlane(rowptr[wave]);
    int end = __builtin_amdgcn_readfirstlane(rowptr[wave + 1]);
    float ad = __uint_as_float(__builtin_amdgcn_readfirstlane(__float_as_uint(a_d[wave])));

    const unsigned int* H32 = (const unsigned int*)H;  // 32 uints/row
    float acc0 = 0.f, acc1 = 0.f, wsum = 0.f;
    int base = beg;
    for (; base + 16 <= end; base += 16) {
        int s[8];
        unsigned int v[8];
        #pragma unroll
        for (int j = 0; j < 8; ++j)
            s[j] = perm[base + h + 2 * j];
        #pragma unroll
        for (int j = 0; j < 8; ++j)
            v[j] = H32[(long long)s[j] * 32 + c];
        #pragma unroll
        for (int j = 0; j < 8; ++j) {
            float t = a_s[s[j]] + ad;
            t = t > 0.f ? t : NEG_SLOPE * t;
            float w = __expf(t);
            acc0 += w * bflo(v[j]);
            acc1 += w * bfhi(v[j]);
            wsum += w;
        }
    }
    for (; base + 8 <= end; base += 8) {
        int s[4];
        unsigned int v[4];
        #pragma unroll
        for (int j = 0; j < 4; ++j)
            s[j] = perm[base + h + 2 * j];
        #pragma unroll
        for (int j = 0; j < 4; ++j)
            v[j] = H32[(long long)s[j] * 32 + c];
        #pragma unroll
        for (int j = 0; j < 4; ++j) {
            float t = a_s[s[j]] + ad;
            t = t > 0.f ? t : NEG_SLOPE * t;
            float w = __expf(t);
            acc0 += w * bflo(v[j]);
            acc1 += w * bfhi(v[j]);
            wsum += w;
        }
    }
    for (int i = base + h; i < end; i += 2) {
        int s = perm[i];
        unsigned int v = H32[(long long)s * 32 + c];
        float t = a_s[s] + ad;
        t = t > 0.f ? t : NEG_SLOPE * t;
        float w = __expf(t);
        acc0 += w * bflo(v); acc1 += w * bfhi(v);
        wsum += w;
    }
    acc0 += __shfl_xor(acc0, 32);
    acc1 += __shfl_xor(acc1, 32);
    wsum += __shfl_xor(wsum, 32);
    if (h == 0) {
        float inv = (wsum > 0.f) ? __fdividef(1.f, wsum) : 0.f;
        float2 o;
        o.x = acc0 * inv + bias[2 * c];
        o.y = acc1 * inv + bias[2 * c + 1];
        *(float2*)(out + (long long)wave * 64 + 2 * c) = o;
    }
}

extern "C" void kernel_launch(void* const* d_in, const int* in_sizes, int n_in,
                              void* d_out, int out_size, void* d_ws, size_t ws_size,
                              hipStream_t stream) {
    const float* x   = (const float*)d_in[0];
    const int*   ei  = (const int*)d_in[1];
    const float* Ws1 = (const float*)d_in[2];
    const float* Wd1 = (const float*)d_in[3];
    const float* as1 = (const float*)d_in[4];
    const float* ad1 = (const float*)d_in[5];
    const float* b1  = (const float*)d_in[6];
    const float* Ws2 = (const float*)d_in[7];
    const float* Wd2 = (const float*)d_in[8];
    const float* as2 = (const float*)d_in[9];
    const float* ad2 = (const float*)d_in[10];
    const float* b2  = (const float*)d_in[11];
    float* out = (float*)d_out;

    const int N = in_sizes[0] / F_IN;   // 100000
    const int E = in_sizes[1] / 2;      // 1600000
    const int* srcs = ei;
    const int* dsts = ei + E;

    // Workspace (~60 MB). rank aliases x2bf (dead before k_agg128 writes it).
    unsigned short* hbuf = (unsigned short*)d_ws;              // N*128 bf16
    unsigned short* x2bf = hbuf + (size_t)N * 128;             // N*128 bf16
    int*   perm   = (int*)(x2bf + (size_t)N * 128);            // E (src only)
    float* a_s1   = (float*)(perm + E);
    float* a_d1   = a_s1 + N;
    float* a_s2   = a_d1 + N;
    float* a_d2   = a_s2 + N;
    int*   cnt    = (int*)(a_d2 + N);                          // N
    int*   rowptr = cnt + N;                                   // N+1 (pad to +4)
    int*   bsum   = rowptr + N + 4;                            // 64
    unsigned short* w1hi = (unsigned short*)(bsum + 64);       // 16384 (swizzled)
    unsigned short* w1lo = w1hi + 16384;
    unsigned short* w2hi = w1lo + 16384;                       // 8192 (swizzled)
    unsigned short* w2lo = w2hi + 8192;
    float* vecs   = (float*)(w2lo + 8192);                     // 512
    int*   rank   = (int*)x2bf;                                // E (alias)

    const int nb = (N + SCAN_CHUNK - 1) / SCAN_CHUNK;

    // ---- prep (cnt zero + attention vecs + swizzled W hi/lo) ----
    k_prep<<<(N + 255) / 256, 256, 0, stream>>>(Ws1, Wd1, as1, ad1, Ws2, Wd2,
                                                as2, ad2, vecs, cnt,
                                                w1hi, w1lo, w2hi, w2lo, N);
    // ---- CSR build (once, reused by both layers) ----
    k_hist<<<(E / 4 + 255) / 256, 256, 0, stream>>>(dsts, cnt, rank, E);
    k_blocksum<<<nb, 256, 0, stream>>>(cnt, bsum, N);
    k_scan_chunks<<<nb, 256, 0, stream>>>(cnt, bsum, rowptr, nb, N);
    k_place<<<(E / 4 + 255) / 256, 256, 0, stream>>>(srcs, dsts, rowptr, rank, perm, E);

    // ---- Layer 1: fp32 X, split-bf16 MFMA ----
    k_gemm_mfma<128, false><<<(N + 127) / 128, 256, 0, stream>>>(
        x, w1hi, w1lo, vecs, vecs + 128, hbuf, a_s1, a_d1, N);
    k_agg128<<<(N + 3) / 4, 256, 0, stream>>>(
        rowptr, perm, a_s1, a_d1, hbuf, b1, x2bf, N);

    // ---- Layer 2: bf16 X (relu'd, b1 folded in by agg) ----
    k_gemm_mfma<64, true><<<(N + 127) / 128, 256, 0, stream>>>(
        x2bf, w2hi, w2lo, vecs + 256, vecs + 384, hbuf, a_s2, a_d2, N);
    k_agg64<<<(N + 3) / 4, 256, 0, stream>>>(
        rowptr, perm, a_s2, a_d2, hbuf, b2, out, N);
}